// Round 12
// baseline (311.886 us; speedup 1.0000x reference)
//
#include <hip/hip_runtime.h>
#include <cmath>

typedef unsigned int uint32;

__device__ __forceinline__ uint32 pack_bf16x2(float a, float b) {
    uint32 ua = __float_as_uint(a), ub = __float_as_uint(b);
    ua = (ua + 0x7fffu + ((ua >> 16) & 1u)) >> 16;   // RNE
    ub = (ub + 0x7fffu + ((ub >> 16) & 1u)) >> 16;
    return ua | (ub << 16);
}

// ---------------- GEMM body: GAT layer pre-pass ----------------
template<int K, int NCOL, int TN>
__device__ __forceinline__ void gemm_body(int bid, const float* __restrict__ X,
                                          const float* __restrict__ W,
                                          const float* __restrict__ v1,
                                          const float* __restrict__ v2,
                                          uint32* __restrict__ H16,
                                          float* __restrict__ AS, float* __restrict__ AD,
                                          int n_nodes) {
    const int t = threadIdx.x;
    const int tx = t & 15, ty = t >> 4;
    const int c0 = tx * TN;
    const int m0 = ty * 4;
    const int node0 = bid * 64;

    __shared__ float As[16][68];
    __shared__ float Bs[16][NCOL];

    float acc[4][TN];
#pragma unroll
    for (int i = 0; i < 4; i++)
#pragma unroll
        for (int j = 0; j < TN; j++) acc[i][j] = 0.f;

    const int am = t >> 2, akq = t & 3;

    for (int kb = 0; kb < K; kb += 16) {
        float4 av = make_float4(0.f, 0.f, 0.f, 0.f);
        int anode = node0 + am;
        if (anode < n_nodes)
            av = *reinterpret_cast<const float4*>(X + (size_t)anode * K + kb + akq * 4);
        As[akq * 4 + 0][am] = av.x;
        As[akq * 4 + 1][am] = av.y;
        As[akq * 4 + 2][am] = av.z;
        As[akq * 4 + 3][am] = av.w;
        {
            const float4* wsrc = reinterpret_cast<const float4*>(W + (size_t)kb * NCOL);
            float4* bdst = reinterpret_cast<float4*>(&Bs[0][0]);
            for (int i = t; i < 16 * NCOL / 4; i += 256) bdst[i] = wsrc[i];
        }
        __syncthreads();
#pragma unroll
        for (int k = 0; k < 16; k++) {
            float4 a4 = *reinterpret_cast<const float4*>(&As[k][m0]);
            float a[4] = {a4.x, a4.y, a4.z, a4.w};
            float b[TN];
#pragma unroll
            for (int j = 0; j < TN / 2; j++) {
                float2 b2 = *reinterpret_cast<const float2*>(&Bs[k][c0 + 2 * j]);
                b[2 * j] = b2.x; b[2 * j + 1] = b2.y;
            }
#pragma unroll
            for (int i = 0; i < 4; i++)
#pragma unroll
                for (int j = 0; j < TN; j++)
                    acc[i][j] = fmaf(a[i], b[j], acc[i][j]);
        }
        __syncthreads();
    }

    __shared__ float s_as[64][16];
    __shared__ float s_ad[64][16];
#pragma unroll
    for (int i = 0; i < 4; i++) {
        int node = node0 + m0 + i;
        float asp = 0.f, adp = 0.f;
#pragma unroll
        for (int j = 0; j < TN; j++) {
            asp = fmaf(acc[i][j], v1[c0 + j], asp);
            adp = fmaf(acc[i][j], v2[c0 + j], adp);
        }
        s_as[m0 + i][tx] = asp;
        s_ad[m0 + i][tx] = adp;
        if (node < n_nodes) {
#pragma unroll
            for (int j = 0; j < TN / 2; j++) {
                H16[(size_t)node * 48 + tx * (TN / 2) + j] =
                    pack_bf16x2(acc[i][2 * j], acc[i][2 * j + 1]);
            }
        }
    }
    __syncthreads();
    int m = t >> 2, head = t & 3;
    int node = node0 + m;
    if (node < n_nodes) {
        float s1 = s_as[m][head * 4 + 0] + s_as[m][head * 4 + 1]
                 + s_as[m][head * 4 + 2] + s_as[m][head * 4 + 3];
        float s2 = s_ad[m][head * 4 + 0] + s_ad[m][head * 4 + 1]
                 + s_ad[m][head * 4 + 2] + s_ad[m][head * 4 + 3];
        AS[(size_t)node * 4 + head] = s1;
        AD[(size_t)node * 4 + head] = s2;
    }
}

template<int K, int NCOL, int TN>
__global__ __launch_bounds__(256)
void tiled_gemm_kernel(const float* __restrict__ X, const float* __restrict__ W,
                       const float* __restrict__ v1, const float* __restrict__ v2,
                       uint32* __restrict__ H16, float* __restrict__ AS,
                       float* __restrict__ AD, int n_nodes) {
    gemm_body<K, NCOL, TN>(blockIdx.x, X, W, v1, v2, H16, AS, AD, n_nodes);
}

// layer-1 GEMM with degree-histogram fused into trailing blocks
template<int K, int NCOL, int TN>
__global__ __launch_bounds__(256)
void gemm_hist_kernel(const float* __restrict__ X, const float* __restrict__ W,
                      const float* __restrict__ v1, const float* __restrict__ v2,
                      uint32* __restrict__ H16, float* __restrict__ AS, float* __restrict__ AD,
                      int n_nodes, int nb_gemm,
                      const int* __restrict__ dst, int* __restrict__ deg, int E) {
    if ((int)blockIdx.x < nb_gemm) {
        gemm_body<K, NCOL, TN>(blockIdx.x, X, W, v1, v2, H16, AS, AD, n_nodes);
    } else {
        int tid = (blockIdx.x - nb_gemm) * 256 + threadIdx.x;
        int stride = (gridDim.x - nb_gemm) * 256;
        for (int e = tid; e < E; e += stride) atomicAdd(&deg[dst[e]], 1);
    }
}

// ---------------- CSR scan ----------------
__global__ void scan_bsum_kernel(const int* __restrict__ deg, int* __restrict__ bsum, int n) {
    __shared__ int s[256];
    int t = threadIdx.x;
    int base = blockIdx.x * 1024;
    int sum = 0;
#pragma unroll
    for (int j = 0; j < 4; j++) {
        int i = base + j * 256 + t;
        if (i < n) sum += deg[i] + 1;   // +1 self-loop
    }
    s[t] = sum;
    __syncthreads();
    for (int off = 128; off; off >>= 1) {
        if (t < off) s[t] += s[t + off];
        __syncthreads();
    }
    if (t == 0) bsum[blockIdx.x] = s[0];
}

__global__ void scan_local_kernel(const int* __restrict__ deg, const int* __restrict__ bsum,
                                  int nb, int* __restrict__ rowptr, int* __restrict__ pos,
                                  int n) {
    __shared__ int s[256];
    __shared__ int boff[257];
    int t = threadIdx.x;
    if (t < nb) boff[t] = bsum[t];
    __syncthreads();
    if (t == 0) {
        int run = 0;
        for (int i = 0; i < nb; i++) { int v = boff[i]; boff[i] = run; run += v; }
        boff[nb] = run;
    }
    __syncthreads();
    if (blockIdx.x == 0 && t == 0) rowptr[n] = boff[nb];

    int base = blockIdx.x * 1024;
    int d[4];
    int sum = 0;
#pragma unroll
    for (int j = 0; j < 4; j++) {
        int i = base + t * 4 + j;
        d[j] = (i < n) ? deg[i] + 1 : 0;
        sum += d[j];
    }
    s[t] = sum;
    __syncthreads();
    for (int off = 1; off < 256; off <<= 1) {
        int x = (t >= off) ? s[t - off] : 0;
        __syncthreads();
        s[t] += x;
        __syncthreads();
    }
    int run = boff[blockIdx.x] + s[t] - sum;
#pragma unroll
    for (int j = 0; j < 4; j++) {
        int i = base + t * 4 + j;
        if (i < n) { rowptr[i] = run; pos[i] = run; }
        run += d[j];
    }
}

__global__ void fill_kernel(const int* __restrict__ src, const int* __restrict__ dst,
                            int* __restrict__ pos, int* __restrict__ col, int E, int N) {
    int i = blockIdx.x * blockDim.x + threadIdx.x;
    if (i < E) {
        int p = atomicAdd(&pos[dst[i]], 1);
        col[p] = src[i];
    } else if (i < E + N) {
        int n = i - E;
        int p = atomicAdd(&pos[n], 1);
        col[p] = n;
    }
}

// ---------------- GAT aggregation layer 1: EXACT R9 body (known-good compile) ----------------
__global__ __launch_bounds__(256)
void gat_gather1_kernel(const uint32* __restrict__ H16, const float* __restrict__ AS,
                        const float* __restrict__ AD, const int* __restrict__ rowptr,
                        const int* __restrict__ col, const float* __restrict__ bias,
                        float* __restrict__ OUT, int n_nodes) {
    int wid = threadIdx.x >> 6, lane = threadIdx.x & 63;
    int n = blockIdx.x * 4 + wid;
    if (n >= n_nodes) return;   // wave-uniform exit
    int beg = rowptr[n], end = rowptr[n + 1];

    int h = lane & 3, slot = lane >> 2;
    float ad_n = AD[(size_t)n * 4 + h];

    int c = lane;                       // bf16-pair (uint) index within row of 48
    bool cown = c < 48;
    int head_c = cown ? (c / 12) : 0;   // head of channels (2c,2c+1)
    const uint32* __restrict__ Hc = H16 + c;

    float denom = 0.f;
    float2 acc0 = make_float2(0.f, 0.f), acc1 = make_float2(0.f, 0.f);
    float2 acc2 = make_float2(0.f, 0.f), acc3 = make_float2(0.f, 0.f);
    float2 acc4 = make_float2(0.f, 0.f), acc5 = make_float2(0.f, 0.f);
    float2 acc6 = make_float2(0.f, 0.f), acc7 = make_float2(0.f, 0.f);

    for (int base = beg; base < end; base += 16) {
        int ce = base + slot;
        int s_e = 0;
        float ex = 0.f;
        if (ce < end) {
            s_e = col[ce];
            float v = AS[(size_t)s_e * 4 + h] + ad_n;
            v = v > 0.f ? v : 0.2f * v;
            ex = __expf(v);             // bounded scores -> shift-free softmax safe
        }
        denom += ex;
        int cnt = end - base;           // wave-uniform

        int sbv[16];
        float wv[16];
#pragma unroll
        for (int i = 0; i < 16; i++) {
            sbv[i] = __shfl(s_e, i * 4, 64);
            wv[i]  = __shfl(ex,  i * 4 + head_c, 64);
        }

#pragma unroll
        for (int g = 0; g < 16; g += 8) {
            if (g < cnt && cown) {
                uint32 u0 = Hc[(size_t)sbv[g + 0] * 48];
                uint32 u1 = Hc[(size_t)sbv[g + 1] * 48];
                uint32 u2 = Hc[(size_t)sbv[g + 2] * 48];
                uint32 u3 = Hc[(size_t)sbv[g + 3] * 48];
                uint32 u4 = Hc[(size_t)sbv[g + 4] * 48];
                uint32 u5 = Hc[(size_t)sbv[g + 5] * 48];
                uint32 u6 = Hc[(size_t)sbv[g + 6] * 48];
                uint32 u7 = Hc[(size_t)sbv[g + 7] * 48];
                acc0.x = fmaf(__uint_as_float(u0 << 16), wv[g + 0], acc0.x);
                acc0.y = fmaf(__uint_as_float(u0 & 0xffff0000u), wv[g + 0], acc0.y);
                acc1.x = fmaf(__uint_as_float(u1 << 16), wv[g + 1], acc1.x);
                acc1.y = fmaf(__uint_as_float(u1 & 0xffff0000u), wv[g + 1], acc1.y);
                acc2.x = fmaf(__uint_as_float(u2 << 16), wv[g + 2], acc2.x);
                acc2.y = fmaf(__uint_as_float(u2 & 0xffff0000u), wv[g + 2], acc2.y);
                acc3.x = fmaf(__uint_as_float(u3 << 16), wv[g + 3], acc3.x);
                acc3.y = fmaf(__uint_as_float(u3 & 0xffff0000u), wv[g + 3], acc3.y);
                acc4.x = fmaf(__uint_as_float(u4 << 16), wv[g + 4], acc4.x);
                acc4.y = fmaf(__uint_as_float(u4 & 0xffff0000u), wv[g + 4], acc4.y);
                acc5.x = fmaf(__uint_as_float(u5 << 16), wv[g + 5], acc5.x);
                acc5.y = fmaf(__uint_as_float(u5 & 0xffff0000u), wv[g + 5], acc5.y);
                acc6.x = fmaf(__uint_as_float(u6 << 16), wv[g + 6], acc6.x);
                acc6.y = fmaf(__uint_as_float(u6 & 0xffff0000u), wv[g + 6], acc6.y);
                acc7.x = fmaf(__uint_as_float(u7 << 16), wv[g + 7], acc7.x);
                acc7.y = fmaf(__uint_as_float(u7 & 0xffff0000u), wv[g + 7], acc7.y);
            }
        }
    }

#pragma unroll
    for (int m = 4; m <= 32; m <<= 1)
        denom += __shfl_xor(denom, m, 64);
    float den = __shfl(denom, head_c, 64);

    if (cown) {
        float2 a;
        a.x = ((acc0.x + acc1.x) + (acc2.x + acc3.x)) + ((acc4.x + acc5.x) + (acc6.x + acc7.x));
        a.y = ((acc0.y + acc1.y) + (acc2.y + acc3.y)) + ((acc4.y + acc5.y) + (acc6.y + acc7.y));
        float2 b2 = reinterpret_cast<const float2*>(bias)[c];
        float inv = 1.f / (den + 1e-16f);
        float ox = a.x * inv + b2.x;
        float oy = a.y * inv + b2.y;
        ox = ox > 0.f ? ox : (__expf(ox) - 1.f);   // ELU
        oy = oy > 0.f ? oy : (__expf(oy) - 1.f);
        reinterpret_cast<float2*>(OUT)[(size_t)n * 48 + c] = make_float2(ox, oy);
    }
}

// ---------------- GAT aggregation layer 2: same body + fused gate MLP ----------------
__global__ __launch_bounds__(256)
void gat_gather2_gate_kernel(const uint32* __restrict__ H16, const float* __restrict__ AS,
                             const float* __restrict__ AD, const int* __restrict__ rowptr,
                             const int* __restrict__ col, const float* __restrict__ bias,
                             float* __restrict__ OUT, int n_nodes,
                             const float* __restrict__ gW1, const float* __restrict__ gb1,
                             const float* __restrict__ gw2, const float* __restrict__ gb2,
                             float* __restrict__ gatev) {
    __shared__ float sh_h[4][96];
    int wid = threadIdx.x >> 6, lane = threadIdx.x & 63;
    int n = blockIdx.x * 4 + wid;
    if (n >= n_nodes) return;   // wave-uniform exit
    int beg = rowptr[n], end = rowptr[n + 1];

    int h = lane & 3, slot = lane >> 2;
    float ad_n = AD[(size_t)n * 4 + h];

    int c = lane;
    bool cown = c < 48;
    int head_c = cown ? (c / 12) : 0;
    const uint32* __restrict__ Hc = H16 + c;

    float denom = 0.f;
    float2 acc0 = make_float2(0.f, 0.f), acc1 = make_float2(0.f, 0.f);
    float2 acc2 = make_float2(0.f, 0.f), acc3 = make_float2(0.f, 0.f);
    float2 acc4 = make_float2(0.f, 0.f), acc5 = make_float2(0.f, 0.f);
    float2 acc6 = make_float2(0.f, 0.f), acc7 = make_float2(0.f, 0.f);

    for (int base = beg; base < end; base += 16) {
        int ce = base + slot;
        int s_e = 0;
        float ex = 0.f;
        if (ce < end) {
            s_e = col[ce];
            float v = AS[(size_t)s_e * 4 + h] + ad_n;
            v = v > 0.f ? v : 0.2f * v;
            ex = __expf(v);
        }
        denom += ex;
        int cnt = end - base;

        int sbv[16];
        float wv[16];
#pragma unroll
        for (int i = 0; i < 16; i++) {
            sbv[i] = __shfl(s_e, i * 4, 64);
            wv[i]  = __shfl(ex,  i * 4 + head_c, 64);
        }

#pragma unroll
        for (int g = 0; g < 16; g += 8) {
            if (g < cnt && cown) {
                uint32 u0 = Hc[(size_t)sbv[g + 0] * 48];
                uint32 u1 = Hc[(size_t)sbv[g + 1] * 48];
                uint32 u2 = Hc[(size_t)sbv[g + 2] * 48];
                uint32 u3 = Hc[(size_t)sbv[g + 3] * 48];
                uint32 u4 = Hc[(size_t)sbv[g + 4] * 48];
                uint32 u5 = Hc[(size_t)sbv[g + 5] * 48];
                uint32 u6 = Hc[(size_t)sbv[g + 6] * 48];
                uint32 u7 = Hc[(size_t)sbv[g + 7] * 48];
                acc0.x = fmaf(__uint_as_float(u0 << 16), wv[g + 0], acc0.x);
                acc0.y = fmaf(__uint_as_float(u0 & 0xffff0000u), wv[g + 0], acc0.y);
                acc1.x = fmaf(__uint_as_float(u1 << 16), wv[g + 1], acc1.x);
                acc1.y = fmaf(__uint_as_float(u1 & 0xffff0000u), wv[g + 1], acc1.y);
                acc2.x = fmaf(__uint_as_float(u2 << 16), wv[g + 2], acc2.x);
                acc2.y = fmaf(__uint_as_float(u2 & 0xffff0000u), wv[g + 2], acc2.y);
                acc3.x = fmaf(__uint_as_float(u3 << 16), wv[g + 3], acc3.x);
                acc3.y = fmaf(__uint_as_float(u3 & 0xffff0000u), wv[g + 3], acc3.y);
                acc4.x = fmaf(__uint_as_float(u4 << 16), wv[g + 4], acc4.x);
                acc4.y = fmaf(__uint_as_float(u4 & 0xffff0000u), wv[g + 4], acc4.y);
                acc5.x = fmaf(__uint_as_float(u5 << 16), wv[g + 5], acc5.x);
                acc5.y = fmaf(__uint_as_float(u5 & 0xffff0000u), wv[g + 5], acc5.y);
                acc6.x = fmaf(__uint_as_float(u6 << 16), wv[g + 6], acc6.x);
                acc6.y = fmaf(__uint_as_float(u6 & 0xffff0000u), wv[g + 6], acc6.y);
                acc7.x = fmaf(__uint_as_float(u7 << 16), wv[g + 7], acc7.x);
                acc7.y = fmaf(__uint_as_float(u7 & 0xffff0000u), wv[g + 7], acc7.y);
            }
        }
    }

#pragma unroll
    for (int m = 4; m <= 32; m <<= 1)
        denom += __shfl_xor(denom, m, 64);
    float den = __shfl(denom, head_c, 64);

    if (cown) {
        float2 a;
        a.x = ((acc0.x + acc1.x) + (acc2.x + acc3.x)) + ((acc4.x + acc5.x) + (acc6.x + acc7.x));
        a.y = ((acc0.y + acc1.y) + (acc2.y + acc3.y)) + ((acc4.y + acc5.y) + (acc6.y + acc7.y));
        float2 b2 = reinterpret_cast<const float2*>(bias)[c];
        float inv = 1.f / (den + 1e-16f);
        float ox = a.x * inv + b2.x;
        float oy = a.y * inv + b2.y;
        ox = ox > 0.f ? ox : (__expf(ox) - 1.f);   // ELU
        oy = oy > 0.f ? oy : (__expf(oy) - 1.f);
        reinterpret_cast<float2*>(OUT)[(size_t)n * 48 + c] = make_float2(ox, oy);
        sh_h[wid][2 * c] = ox;
        sh_h[wid][2 * c + 1] = oy;
    }

    __builtin_amdgcn_wave_barrier();   // wave-local LDS write->read ordering
    float gv = 0.f;
    if (lane < 48) {
        float aj = gb1[lane];
        for (int cc = 0; cc < 96; cc++)
            aj = fmaf(sh_h[wid][cc], gW1[cc * 48 + lane], aj);
        aj = fmaxf(aj, 0.f);
        gv = aj * gw2[lane];
    }
#pragma unroll
    for (int m = 1; m <= 32; m <<= 1)
        gv += __shfl_xor(gv, m, 64);
    if (lane == 0) gatev[n] = gv + gb2[0];
}

// ---------------- pooling: unnormalized weighted segment-sum + denom ----------------
__global__ __launch_bounds__(384)
void pool_accum_kernel(const float* __restrict__ H2, const float* __restrict__ gate,
                       const int* __restrict__ batch, int n_nodes,
                       float* __restrict__ pooled, float* __restrict__ denp) {
    const int NPB = 256;
    int t = threadIdx.x;
    int group = t / 96;
    int c = t - group * 96;
    if (group >= 4) return;
    int nbeg = blockIdx.x * NPB;
    int nend = min(nbeg + NPB, n_nodes);

    float acc = 0.f, dacc = 0.f;
    int curg = -1;
    for (int i = nbeg + group; i < nend; i += 4) {
        int g = batch[i];
        if (g != curg) {
            if (curg >= 0) {
                atomicAdd(&pooled[(size_t)curg * 96 + c], acc);
                if (c == 0) atomicAdd(&denp[curg], dacc);
            }
            acc = 0.f; dacc = 0.f;
            curg = g;
        }
        float ge = __expf(gate[i]);
        acc = fmaf(ge, H2[(size_t)i * 96 + c], acc);
        if (c == 0) dacc += ge;
    }
    if (curg >= 0) {
        atomicAdd(&pooled[(size_t)curg * 96 + c], acc);
        if (c == 0) atomicAdd(&denp[curg], dacc);
    }
}

// ---------------- final MLP ----------------
__global__ void final_kernel(const float* __restrict__ pooled, const float* __restrict__ denp,
                             const float* __restrict__ f_w1, const float* __restrict__ f_b1,
                             const float* __restrict__ f_w2, const float* __restrict__ f_b2,
                             float* __restrict__ out) {
    int g = blockIdx.x, t = threadIdx.x;   // 96 threads
    __shared__ float sp[96], sh[96];
    sp[t] = pooled[(size_t)g * 96 + t] / (denp[g] + 1e-16f);
    __syncthreads();
    float a = f_b1[t];
    for (int k = 0; k < 96; k++) a = fmaf(sp[k], f_w1[k * 96 + t], a);
    sh[t] = fmaxf(a, 0.f);
    __syncthreads();
    if (t < 3) {
        float o = f_b2[t];
        for (int k = 0; k < 96; k++) o = fmaf(sh[k], f_w2[k * 3 + t], o);
        out[g * 3 + t] = o;
    }
}

// ---------------- launch ----------------
extern "C" void kernel_launch(void* const* d_in, const int* in_sizes, int n_in,
                              void* d_out, int out_size, void* d_ws, size_t ws_size,
                              hipStream_t stream) {
    const float* x    = (const float*)d_in[0];
    const int*   ei   = (const int*)d_in[1];
    const int*   batch= (const int*)d_in[2];
    const float* W1   = (const float*)d_in[4];
    const float* as1  = (const float*)d_in[5];
    const float* ad1  = (const float*)d_in[6];
    const float* b1   = (const float*)d_in[7];
    const float* W2   = (const float*)d_in[8];
    const float* as2  = (const float*)d_in[9];
    const float* ad2  = (const float*)d_in[10];
    const float* b2   = (const float*)d_in[11];
    const float* g_w1 = (const float*)d_in[12];
    const float* g_b1 = (const float*)d_in[13];
    const float* g_w2 = (const float*)d_in[14];
    const float* g_b2 = (const float*)d_in[15];
    const float* f_w1 = (const float*)d_in[16];
    const float* f_b1 = (const float*)d_in[17];
    const float* f_w2 = (const float*)d_in[18];
    const float* f_b2 = (const float*)d_in[19];
    float* out = (float*)d_out;

    int N = in_sizes[0] / 128;
    int E = in_sizes[1] / 2;
    int G = out_size / 3;
    const int* srcv = ei;
    const int* dstv = ei + E;

    // zero-init region (deg | pooled | denp) -> single memset
    char* base = (char*)d_ws;
    int*   deg    = (int*)base;
    float* pooled = (float*)(base + (size_t)N * 4);
    float* denp   = (float*)(base + (size_t)N * 4 + (size_t)G * 96 * 4);
    size_t zbytes = (size_t)(N + G * 96 + G) * 4;

    char* p = base + ((zbytes + 255) & ~(size_t)255);
    auto alloc = [&](size_t bytes) {
        char* q = p;
        p += (bytes + 255) & ~(size_t)255;
        return q;
    };
    uint32* hA   = (uint32*)alloc((size_t)N * 48 * 4);   // bf16 x2 per uint
    float* hB    = (float*)alloc((size_t)N * 96 * 4);
    float* AS    = (float*)alloc((size_t)N * 4 * 4);
    float* AD    = (float*)alloc((size_t)N * 4 * 4);
    float* gatev = (float*)alloc((size_t)N * 4);
    int*   pos   = (int*)alloc((size_t)N * 4);
    int*   rowptr= (int*)alloc(((size_t)N + 1) * 4);
    int*   bsum  = (int*)alloc((size_t)256 * 4);
    int*   col   = (int*)alloc((size_t)(E + N) * 4);

    const int B = 256;
    int gemm_blocks = (N + 63) / 64;
    int nb_scan = (N + 1023) / 1024;

    hipMemsetAsync(base, 0, zbytes, stream);

    // layer-1 GEMM with fused degree histogram
    gemm_hist_kernel<128, 96, 6><<<gemm_blocks + 256, 256, 0, stream>>>(
        x, W1, as1, ad1, hA, AS, AD, N, gemm_blocks, dstv, deg, E);

    // CSR finish
    scan_bsum_kernel<<<nb_scan, 256, 0, stream>>>(deg, bsum, N);
    scan_local_kernel<<<nb_scan, 256, 0, stream>>>(deg, bsum, nb_scan, rowptr, pos, N);
    fill_kernel<<<(E + N + B - 1) / B, B, 0, stream>>>(srcv, dstv, pos, col, E, N);

    // layer 1 aggregation
    gat_gather1_kernel<<<(N + 3) / 4, 256, 0, stream>>>(
        hA, AS, AD, rowptr, col, b1, hB, N);
    // layer 2
    tiled_gemm_kernel<96, 96, 6><<<gemm_blocks, 256, 0, stream>>>(
        hB, W2, as2, ad2, hA, AS, AD, N);
    // layer 2 aggregation + fused gate MLP
    gat_gather2_gate_kernel<<<(N + 3) / 4, 256, 0, stream>>>(
        hA, AS, AD, rowptr, col, b2, hB, N, g_w1, g_b1, g_w2, g_b2, gatev);

    // pooling
    pool_accum_kernel<<<(N + 255) / 256, 384, 0, stream>>>(
        hB, gatev, batch, N, pooled, denp);
    final_kernel<<<G, 96, 0, stream>>>(pooled, denp, f_w1, f_b1, f_w2, f_b2, out);
}

// Round 13
// 305.653 us; speedup vs baseline: 1.0204x; 1.0204x over previous
//
#include <hip/hip_runtime.h>
#include <cmath>

typedef unsigned int uint32;

__device__ __forceinline__ uint32 pack_bf16x2(float a, float b) {
    uint32 ua = __float_as_uint(a), ub = __float_as_uint(b);
    ua = (ua + 0x7fffu + ((ua >> 16) & 1u)) >> 16;   // RNE
    ub = (ub + 0x7fffu + ((ub >> 16) & 1u)) >> 16;
    return ua | (ub << 16);
}

// ---------------- GEMM body (shared by plain + fused-hist kernels) ----------------
// MODE 0: GAT layer pre-pass. H16 = bf16(X@W), AS/AD via epilogue LDS reduce.
// MODE 1: gate MLP. Hf[node] = relu(X@W + g_b1) @ g_w2 + g_b2.
template<int K, int NCOL, int TN, int MODE>
__device__ __forceinline__ void gemm_body(int bid, const float* __restrict__ X,
                                          const float* __restrict__ W,
                                          const float* __restrict__ v1,
                                          const float* __restrict__ v2,
                                          const float* __restrict__ v3,
                                          uint32* __restrict__ H16, float* __restrict__ Hf,
                                          float* __restrict__ AS, float* __restrict__ AD,
                                          int n_nodes) {
    const int t = threadIdx.x;
    const int tx = t & 15, ty = t >> 4;
    const int c0 = tx * TN;
    const int m0 = ty * 4;
    const int node0 = bid * 64;

    __shared__ float As[16][68];
    __shared__ float Bs[16][NCOL];

    float acc[4][TN];
#pragma unroll
    for (int i = 0; i < 4; i++)
#pragma unroll
        for (int j = 0; j < TN; j++) acc[i][j] = 0.f;

    const int am = t >> 2, akq = t & 3;

    for (int kb = 0; kb < K; kb += 16) {
        float4 av = make_float4(0.f, 0.f, 0.f, 0.f);
        int anode = node0 + am;
        if (anode < n_nodes)
            av = *reinterpret_cast<const float4*>(X + (size_t)anode * K + kb + akq * 4);
        As[akq * 4 + 0][am] = av.x;
        As[akq * 4 + 1][am] = av.y;
        As[akq * 4 + 2][am] = av.z;
        As[akq * 4 + 3][am] = av.w;
        {
            const float4* wsrc = reinterpret_cast<const float4*>(W + (size_t)kb * NCOL);
            float4* bdst = reinterpret_cast<float4*>(&Bs[0][0]);
            for (int i = t; i < 16 * NCOL / 4; i += 256) bdst[i] = wsrc[i];
        }
        __syncthreads();
#pragma unroll
        for (int k = 0; k < 16; k++) {
            float4 a4 = *reinterpret_cast<const float4*>(&As[k][m0]);
            float a[4] = {a4.x, a4.y, a4.z, a4.w};
            float b[TN];
            if constexpr ((TN & 1) == 0) {
#pragma unroll
                for (int j = 0; j < TN / 2; j++) {
                    float2 b2 = *reinterpret_cast<const float2*>(&Bs[k][c0 + 2 * j]);
                    b[2 * j] = b2.x; b[2 * j + 1] = b2.y;
                }
            } else {
#pragma unroll
                for (int j = 0; j < TN; j++) b[j] = Bs[k][c0 + j];
            }
#pragma unroll
            for (int i = 0; i < 4; i++)
#pragma unroll
                for (int j = 0; j < TN; j++)
                    acc[i][j] = fmaf(a[i], b[j], acc[i][j]);
        }
        __syncthreads();
    }

    if constexpr (MODE == 0) {
        __shared__ float s_as[64][16];
        __shared__ float s_ad[64][16];
#pragma unroll
        for (int i = 0; i < 4; i++) {
            int node = node0 + m0 + i;
            float asp = 0.f, adp = 0.f;
#pragma unroll
            for (int j = 0; j < TN; j++) {
                asp = fmaf(acc[i][j], v1[c0 + j], asp);
                adp = fmaf(acc[i][j], v2[c0 + j], adp);
            }
            s_as[m0 + i][tx] = asp;
            s_ad[m0 + i][tx] = adp;
            if (node < n_nodes) {
#pragma unroll
                for (int j = 0; j < TN / 2; j++) {
                    H16[(size_t)node * 48 + tx * (TN / 2) + j] =
                        pack_bf16x2(acc[i][2 * j], acc[i][2 * j + 1]);
                }
            }
        }
        __syncthreads();
        int m = t >> 2, head = t & 3;
        int node = node0 + m;
        if (node < n_nodes) {
            float s1 = s_as[m][head * 4 + 0] + s_as[m][head * 4 + 1]
                     + s_as[m][head * 4 + 2] + s_as[m][head * 4 + 3];
            float s2 = s_ad[m][head * 4 + 0] + s_ad[m][head * 4 + 1]
                     + s_ad[m][head * 4 + 2] + s_ad[m][head * 4 + 3];
            AS[(size_t)node * 4 + head] = s1;
            AD[(size_t)node * 4 + head] = s2;
        }
    } else {
        __shared__ float s_g[64][16];
#pragma unroll
        for (int i = 0; i < 4; i++) {
            float p = 0.f;
#pragma unroll
            for (int j = 0; j < TN; j++) {
                float a = acc[i][j] + v1[c0 + j];
                a = fmaxf(a, 0.f);
                p = fmaf(a, v2[c0 + j], p);
            }
            s_g[m0 + i][tx] = p;
        }
        __syncthreads();
        if (t < 64) {
            int node = node0 + t;
            if (node < n_nodes) {
                float s = 0.f;
#pragma unroll
                for (int j = 0; j < 16; j++) s += s_g[t][j];
                Hf[node] = s + v3[0];
            }
        }
    }
}

template<int K, int NCOL, int TN, int MODE>
__global__ __launch_bounds__(256)
void tiled_gemm_kernel(const float* __restrict__ X, const float* __restrict__ W,
                       const float* __restrict__ v1, const float* __restrict__ v2,
                       const float* __restrict__ v3,
                       uint32* __restrict__ H16, float* __restrict__ Hf,
                       float* __restrict__ AS, float* __restrict__ AD, int n_nodes) {
    gemm_body<K, NCOL, TN, MODE>(blockIdx.x, X, W, v1, v2, v3, H16, Hf, AS, AD, n_nodes);
}

// layer-1 GEMM with degree-histogram fused into trailing blocks (independent work)
template<int K, int NCOL, int TN>
__global__ __launch_bounds__(256)
void gemm_hist_kernel(const float* __restrict__ X, const float* __restrict__ W,
                      const float* __restrict__ v1, const float* __restrict__ v2,
                      uint32* __restrict__ H16, float* __restrict__ AS, float* __restrict__ AD,
                      int n_nodes, int nb_gemm,
                      const int* __restrict__ dst, int* __restrict__ deg, int E) {
    if ((int)blockIdx.x < nb_gemm) {
        gemm_body<K, NCOL, TN, 0>(blockIdx.x, X, W, v1, v2, nullptr, H16, nullptr,
                                  AS, AD, n_nodes);
    } else {
        int tid = (blockIdx.x - nb_gemm) * 256 + threadIdx.x;
        int stride = (gridDim.x - nb_gemm) * 256;
        for (int e = tid; e < E; e += stride) atomicAdd(&deg[dst[e]], 1);
    }
}

// ---------------- CSR scan (2 kernels; block-sum scan folded into local pass) ----------------
__global__ void scan_bsum_kernel(const int* __restrict__ deg, int* __restrict__ bsum, int n) {
    __shared__ int s[256];
    int t = threadIdx.x;
    int base = blockIdx.x * 1024;
    int sum = 0;
#pragma unroll
    for (int j = 0; j < 4; j++) {
        int i = base + j * 256 + t;
        if (i < n) sum += deg[i] + 1;   // +1 self-loop
    }
    s[t] = sum;
    __syncthreads();
    for (int off = 128; off; off >>= 1) {
        if (t < off) s[t] += s[t + off];
        __syncthreads();
    }
    if (t == 0) bsum[blockIdx.x] = s[0];
}

__global__ void scan_local_kernel(const int* __restrict__ deg, const int* __restrict__ bsum,
                                  int nb, int* __restrict__ rowptr, int* __restrict__ pos,
                                  int n) {
    __shared__ int s[256];
    __shared__ int boff[257];
    int t = threadIdx.x;
    if (t < nb) boff[t] = bsum[t];
    __syncthreads();
    if (t == 0) {
        int run = 0;
        for (int i = 0; i < nb; i++) { int v = boff[i]; boff[i] = run; run += v; }
        boff[nb] = run;
    }
    __syncthreads();
    if (blockIdx.x == 0 && t == 0) rowptr[n] = boff[nb];

    int base = blockIdx.x * 1024;
    int d[4];
    int sum = 0;
#pragma unroll
    for (int j = 0; j < 4; j++) {
        int i = base + t * 4 + j;
        d[j] = (i < n) ? deg[i] + 1 : 0;
        sum += d[j];
    }
    s[t] = sum;
    __syncthreads();
    for (int off = 1; off < 256; off <<= 1) {
        int x = (t >= off) ? s[t - off] : 0;
        __syncthreads();
        s[t] += x;
        __syncthreads();
    }
    int run = boff[blockIdx.x] + s[t] - sum;
#pragma unroll
    for (int j = 0; j < 4; j++) {
        int i = base + t * 4 + j;
        if (i < n) { rowptr[i] = run; pos[i] = run; }
        run += d[j];
    }
}

__global__ void fill_kernel(const int* __restrict__ src, const int* __restrict__ dst,
                            int* __restrict__ pos, int* __restrict__ col, int E, int N) {
    int i = blockIdx.x * blockDim.x + threadIdx.x;
    if (i < E) {
        int p = atomicAdd(&pos[dst[i]], 1);
        col[p] = src[i];
    } else if (i < E + N) {
        int n = i - E;
        int p = atomicAdd(&pos[n], 1);
        col[p] = n;
    }
}

// ---------------- GAT aggregation: wave per node, bf16 H rows, no max pass ----------------
__global__ __launch_bounds__(256)
void gat_gather_kernel(const uint32* __restrict__ H16, const float* __restrict__ AS,
                       const float* __restrict__ AD, const int* __restrict__ rowptr,
                       const int* __restrict__ col, const float* __restrict__ bias,
                       float* __restrict__ OUT, int n_nodes) {
    int wid = threadIdx.x >> 6, lane = threadIdx.x & 63;
    int n = blockIdx.x * 4 + wid;
    if (n >= n_nodes) return;   // wave-uniform exit
    int beg = rowptr[n], end = rowptr[n + 1];

    int h = lane & 3, slot = lane >> 2;
    float ad_n = AD[(size_t)n * 4 + h];

    int c = lane;                       // bf16-pair (uint) index within row of 48
    bool cown = c < 48;
    int head_c = cown ? (c / 12) : 0;   // head of channels (2c,2c+1)
    const uint32* __restrict__ Hc = H16 + c;

    float denom = 0.f;
    float2 acc0 = make_float2(0.f, 0.f), acc1 = make_float2(0.f, 0.f);
    float2 acc2 = make_float2(0.f, 0.f), acc3 = make_float2(0.f, 0.f);
    float2 acc4 = make_float2(0.f, 0.f), acc5 = make_float2(0.f, 0.f);
    float2 acc6 = make_float2(0.f, 0.f), acc7 = make_float2(0.f, 0.f);

    for (int base = beg; base < end; base += 16) {
        int ce = base + slot;
        int s_e = 0;
        float ex = 0.f;
        if (ce < end) {
            s_e = col[ce];
            float v = AS[(size_t)s_e * 4 + h] + ad_n;
            v = v > 0.f ? v : 0.2f * v;
            ex = __expf(v);             // bounded scores -> shift-free softmax safe
        }
        denom += ex;
        int cnt = end - base;           // wave-uniform

        int sbv[16];
        float wv[16];
#pragma unroll
        for (int i = 0; i < 16; i++) {
            sbv[i] = __shfl(s_e, i * 4, 64);
            wv[i]  = __shfl(ex,  i * 4 + head_c, 64);
        }

#pragma unroll
        for (int g = 0; g < 16; g += 8) {
            if (g < cnt && cown) {
                uint32 u0 = Hc[(size_t)sbv[g + 0] * 48];
                uint32 u1 = Hc[(size_t)sbv[g + 1] * 48];
                uint32 u2 = Hc[(size_t)sbv[g + 2] * 48];
                uint32 u3 = Hc[(size_t)sbv[g + 3] * 48];
                uint32 u4 = Hc[(size_t)sbv[g + 4] * 48];
                uint32 u5 = Hc[(size_t)sbv[g + 5] * 48];
                uint32 u6 = Hc[(size_t)sbv[g + 6] * 48];
                uint32 u7 = Hc[(size_t)sbv[g + 7] * 48];
                acc0.x = fmaf(__uint_as_float(u0 << 16), wv[g + 0], acc0.x);
                acc0.y = fmaf(__uint_as_float(u0 & 0xffff0000u), wv[g + 0], acc0.y);
                acc1.x = fmaf(__uint_as_float(u1 << 16), wv[g + 1], acc1.x);
                acc1.y = fmaf(__uint_as_float(u1 & 0xffff0000u), wv[g + 1], acc1.y);
                acc2.x = fmaf(__uint_as_float(u2 << 16), wv[g + 2], acc2.x);
                acc2.y = fmaf(__uint_as_float(u2 & 0xffff0000u), wv[g + 2], acc2.y);
                acc3.x = fmaf(__uint_as_float(u3 << 16), wv[g + 3], acc3.x);
                acc3.y = fmaf(__uint_as_float(u3 & 0xffff0000u), wv[g + 3], acc3.y);
                acc4.x = fmaf(__uint_as_float(u4 << 16), wv[g + 4], acc4.x);
                acc4.y = fmaf(__uint_as_float(u4 & 0xffff0000u), wv[g + 4], acc4.y);
                acc5.x = fmaf(__uint_as_float(u5 << 16), wv[g + 5], acc5.x);
                acc5.y = fmaf(__uint_as_float(u5 & 0xffff0000u), wv[g + 5], acc5.y);
                acc6.x = fmaf(__uint_as_float(u6 << 16), wv[g + 6], acc6.x);
                acc6.y = fmaf(__uint_as_float(u6 & 0xffff0000u), wv[g + 6], acc6.y);
                acc7.x = fmaf(__uint_as_float(u7 << 16), wv[g + 7], acc7.x);
                acc7.y = fmaf(__uint_as_float(u7 & 0xffff0000u), wv[g + 7], acc7.y);
            }
        }
    }

#pragma unroll
    for (int m = 4; m <= 32; m <<= 1)
        denom += __shfl_xor(denom, m, 64);
    float den = __shfl(denom, head_c, 64);

    if (cown) {
        float2 a;
        a.x = ((acc0.x + acc1.x) + (acc2.x + acc3.x)) + ((acc4.x + acc5.x) + (acc6.x + acc7.x));
        a.y = ((acc0.y + acc1.y) + (acc2.y + acc3.y)) + ((acc4.y + acc5.y) + (acc6.y + acc7.y));
        float2 b2 = reinterpret_cast<const float2*>(bias)[c];
        float inv = 1.f / (den + 1e-16f);
        float ox = a.x * inv + b2.x;
        float oy = a.y * inv + b2.y;
        ox = ox > 0.f ? ox : (__expf(ox) - 1.f);   // ELU
        oy = oy > 0.f ? oy : (__expf(oy) - 1.f);
        reinterpret_cast<float2*>(OUT)[(size_t)n * 48 + c] = make_float2(ox, oy);
    }
}

// ---------------- pooling: unnormalized weighted segment-sum + denom ----------------
__global__ __launch_bounds__(384)
void pool_accum_kernel(const float* __restrict__ H2, const float* __restrict__ gate,
                       const int* __restrict__ batch, int n_nodes,
                       float* __restrict__ pooled, float* __restrict__ denp) {
    const int NPB = 256;
    int t = threadIdx.x;
    int group = t / 96;
    int c = t - group * 96;
    if (group >= 4) return;
    int nbeg = blockIdx.x * NPB;
    int nend = min(nbeg + NPB, n_nodes);

    float acc = 0.f, dacc = 0.f;
    int curg = -1;
    for (int i = nbeg + group; i < nend; i += 4) {
        int g = batch[i];
        if (g != curg) {
            if (curg >= 0) {
                atomicAdd(&pooled[(size_t)curg * 96 + c], acc);
                if (c == 0) atomicAdd(&denp[curg], dacc);
            }
            acc = 0.f; dacc = 0.f;
            curg = g;
        }
        float ge = __expf(gate[i]);
        acc = fmaf(ge, H2[(size_t)i * 96 + c], acc);
        if (c == 0) dacc += ge;
    }
    if (curg >= 0) {
        atomicAdd(&pooled[(size_t)curg * 96 + c], acc);
        if (c == 0) atomicAdd(&denp[curg], dacc);
    }
}

// ---------------- final MLP (one block per graph); normalizes pooled ----------------
__global__ void final_kernel(const float* __restrict__ pooled, const float* __restrict__ denp,
                             const float* __restrict__ f_w1, const float* __restrict__ f_b1,
                             const float* __restrict__ f_w2, const float* __restrict__ f_b2,
                             float* __restrict__ out) {
    int g = blockIdx.x, t = threadIdx.x;   // 96 threads
    __shared__ float sp[96], sh[96];
    sp[t] = pooled[(size_t)g * 96 + t] / (denp[g] + 1e-16f);
    __syncthreads();
    float a = f_b1[t];
    for (int k = 0; k < 96; k++) a = fmaf(sp[k], f_w1[k * 96 + t], a);
    sh[t] = fmaxf(a, 0.f);
    __syncthreads();
    if (t < 3) {
        float o = f_b2[t];
        for (int k = 0; k < 96; k++) o = fmaf(sh[k], f_w2[k * 3 + t], o);
        out[g * 3 + t] = o;
    }
}

// ---------------- launch ----------------
extern "C" void kernel_launch(void* const* d_in, const int* in_sizes, int n_in,
                              void* d_out, int out_size, void* d_ws, size_t ws_size,
                              hipStream_t stream) {
    const float* x    = (const float*)d_in[0];
    const int*   ei   = (const int*)d_in[1];
    const int*   batch= (const int*)d_in[2];
    const float* W1   = (const float*)d_in[4];
    const float* as1  = (const float*)d_in[5];
    const float* ad1  = (const float*)d_in[6];
    const float* b1   = (const float*)d_in[7];
    const float* W2   = (const float*)d_in[8];
    const float* as2  = (const float*)d_in[9];
    const float* ad2  = (const float*)d_in[10];
    const float* b2   = (const float*)d_in[11];
    const float* g_w1 = (const float*)d_in[12];
    const float* g_b1 = (const float*)d_in[13];
    const float* g_w2 = (const float*)d_in[14];
    const float* g_b2 = (const float*)d_in[15];
    const float* f_w1 = (const float*)d_in[16];
    const float* f_b1 = (const float*)d_in[17];
    const float* f_w2 = (const float*)d_in[18];
    const float* f_b2 = (const float*)d_in[19];
    float* out = (float*)d_out;

    int N = in_sizes[0] / 128;
    int E = in_sizes[1] / 2;
    int G = out_size / 3;
    const int* srcv = ei;
    const int* dstv = ei + E;

    // zero-init region first (deg | pooled | denp) -> single memset
    char* base = (char*)d_ws;
    int*   deg    = (int*)base;
    float* pooled = (float*)(base + (size_t)N * 4);
    float* denp   = (float*)(base + (size_t)N * 4 + (size_t)G * 96 * 4);
    size_t zbytes = (size_t)(N + G * 96 + G) * 4;

    char* p = base + ((zbytes + 255) & ~(size_t)255);
    auto alloc = [&](size_t bytes) {
        char* q = p;
        p += (bytes + 255) & ~(size_t)255;
        return q;
    };
    uint32* hA   = (uint32*)alloc((size_t)N * 48 * 4);   // bf16 x2 per uint
    float* hB    = (float*)alloc((size_t)N * 96 * 4);
    float* AS    = (float*)alloc((size_t)N * 4 * 4);
    float* AD    = (float*)alloc((size_t)N * 4 * 4);
    float* gatev = (float*)alloc((size_t)N * 4);
    int*   pos   = (int*)alloc((size_t)N * 4);
    int*   rowptr= (int*)alloc(((size_t)N + 1) * 4);
    int*   bsum  = (int*)alloc((size_t)256 * 4);
    int*   col   = (int*)alloc((size_t)(E + N) * 4);

    const int B = 256;
    int gemm_blocks = (N + 63) / 64;
    int nb_scan = (N + 1023) / 1024;

    hipMemsetAsync(base, 0, zbytes, stream);

    // layer-1 GEMM with fused degree histogram (independent work overlapped)
    gemm_hist_kernel<128, 96, 6><<<gemm_blocks + 256, 256, 0, stream>>>(
        x, W1, as1, ad1, hA, AS, AD, N, gemm_blocks, dstv, deg, E);

    // CSR finish
    scan_bsum_kernel<<<nb_scan, 256, 0, stream>>>(deg, bsum, N);
    scan_local_kernel<<<nb_scan, 256, 0, stream>>>(deg, bsum, nb_scan, rowptr, pos, N);
    fill_kernel<<<(E + N + B - 1) / B, B, 0, stream>>>(srcv, dstv, pos, col, E, N);

    // layer 1 aggregation
    gat_gather_kernel<<<(N + 3) / 4, 256, 0, stream>>>(hA, AS, AD, rowptr, col, b1, hB, N);
    // layer 2
    tiled_gemm_kernel<96, 96, 6, 0><<<gemm_blocks, 256, 0, stream>>>(
        hB, W2, as2, ad2, nullptr, hA, nullptr, AS, AD, N);
    gat_gather_kernel<<<(N + 3) / 4, 256, 0, stream>>>(hA, AS, AD, rowptr, col, b2, hB, N);

    // pooling
    tiled_gemm_kernel<96, 48, 3, 1><<<gemm_blocks, 256, 0, stream>>>(
        hB, g_w1, g_b1, g_w2, g_b2, nullptr, gatev, nullptr, nullptr, N);
    pool_accum_kernel<<<(N + 255) / 256, 384, 0, stream>>>(
        hB, gatev, batch, N, pooled, denp);
    final_kernel<<<G, 96, 0, stream>>>(pooled, denp, f_w1, f_b1, f_w2, f_b2, out);
}

// Round 14
// 285.006 us; speedup vs baseline: 1.0943x; 1.0724x over previous
//
#include <hip/hip_runtime.h>
#include <cmath>

typedef unsigned int uint32;

__device__ __forceinline__ uint32 pack_bf16x2(float a, float b) {
    uint32 ua = __float_as_uint(a), ub = __float_as_uint(b);
    ua = (ua + 0x7fffu + ((ua >> 16) & 1u)) >> 16;   // RNE
    ub = (ub + 0x7fffu + ((ub >> 16) & 1u)) >> 16;
    return ua | (ub << 16);
}

// ---------------- GEMM body (shared) ----------------
// MODE 0: GAT layer pre-pass. H16 = bf16(X@W), AS/AD via epilogue LDS reduce.
// MODE 1: gate MLP. Hf[node] = relu(X@W + g_b1) @ g_w2 + g_b2.
template<int K, int NCOL, int TN, int MODE>
__device__ __forceinline__ void gemm_body(int bid, const float* __restrict__ X,
                                          const float* __restrict__ W,
                                          const float* __restrict__ v1,
                                          const float* __restrict__ v2,
                                          const float* __restrict__ v3,
                                          uint32* __restrict__ H16, float* __restrict__ Hf,
                                          float* __restrict__ AS, float* __restrict__ AD,
                                          int n_nodes) {
    const int t = threadIdx.x;
    const int tx = t & 15, ty = t >> 4;
    const int c0 = tx * TN;
    const int m0 = ty * 4;
    const int node0 = bid * 64;

    __shared__ float As[16][68];
    __shared__ float Bs[16][NCOL];

    float acc[4][TN];
#pragma unroll
    for (int i = 0; i < 4; i++)
#pragma unroll
        for (int j = 0; j < TN; j++) acc[i][j] = 0.f;

    const int am = t >> 2, akq = t & 3;

    for (int kb = 0; kb < K; kb += 16) {
        float4 av = make_float4(0.f, 0.f, 0.f, 0.f);
        int anode = node0 + am;
        if (anode < n_nodes)
            av = *reinterpret_cast<const float4*>(X + (size_t)anode * K + kb + akq * 4);
        As[akq * 4 + 0][am] = av.x;
        As[akq * 4 + 1][am] = av.y;
        As[akq * 4 + 2][am] = av.z;
        As[akq * 4 + 3][am] = av.w;
        {
            const float4* wsrc = reinterpret_cast<const float4*>(W + (size_t)kb * NCOL);
            float4* bdst = reinterpret_cast<float4*>(&Bs[0][0]);
            for (int i = t; i < 16 * NCOL / 4; i += 256) bdst[i] = wsrc[i];
        }
        __syncthreads();
#pragma unroll
        for (int k = 0; k < 16; k++) {
            float4 a4 = *reinterpret_cast<const float4*>(&As[k][m0]);
            float a[4] = {a4.x, a4.y, a4.z, a4.w};
            float b[TN];
            if constexpr ((TN & 1) == 0) {
#pragma unroll
                for (int j = 0; j < TN / 2; j++) {
                    float2 b2 = *reinterpret_cast<const float2*>(&Bs[k][c0 + 2 * j]);
                    b[2 * j] = b2.x; b[2 * j + 1] = b2.y;
                }
            } else {
#pragma unroll
                for (int j = 0; j < TN; j++) b[j] = Bs[k][c0 + j];
            }
#pragma unroll
            for (int i = 0; i < 4; i++)
#pragma unroll
                for (int j = 0; j < TN; j++)
                    acc[i][j] = fmaf(a[i], b[j], acc[i][j]);
        }
        __syncthreads();
    }

    if constexpr (MODE == 0) {
        __shared__ float s_as[64][16];
        __shared__ float s_ad[64][16];
#pragma unroll
        for (int i = 0; i < 4; i++) {
            int node = node0 + m0 + i;
            float asp = 0.f, adp = 0.f;
#pragma unroll
            for (int j = 0; j < TN; j++) {
                asp = fmaf(acc[i][j], v1[c0 + j], asp);
                adp = fmaf(acc[i][j], v2[c0 + j], adp);
            }
            s_as[m0 + i][tx] = asp;
            s_ad[m0 + i][tx] = adp;
            if (node < n_nodes) {
#pragma unroll
                for (int j = 0; j < TN / 2; j++) {
                    H16[(size_t)node * 48 + tx * (TN / 2) + j] =
                        pack_bf16x2(acc[i][2 * j], acc[i][2 * j + 1]);
                }
            }
        }
        __syncthreads();
        int m = t >> 2, head = t & 3;
        int node = node0 + m;
        if (node < n_nodes) {
            float s1 = s_as[m][head * 4 + 0] + s_as[m][head * 4 + 1]
                     + s_as[m][head * 4 + 2] + s_as[m][head * 4 + 3];
            float s2 = s_ad[m][head * 4 + 0] + s_ad[m][head * 4 + 1]
                     + s_ad[m][head * 4 + 2] + s_ad[m][head * 4 + 3];
            AS[(size_t)node * 4 + head] = s1;
            AD[(size_t)node * 4 + head] = s2;
        }
    } else {
        __shared__ float s_g[64][16];
#pragma unroll
        for (int i = 0; i < 4; i++) {
            float p = 0.f;
#pragma unroll
            for (int j = 0; j < TN; j++) {
                float a = acc[i][j] + v1[c0 + j];
                a = fmaxf(a, 0.f);
                p = fmaf(a, v2[c0 + j], p);
            }
            s_g[m0 + i][tx] = p;
        }
        __syncthreads();
        if (t < 64) {
            int node = node0 + t;
            if (node < n_nodes) {
                float s = 0.f;
#pragma unroll
                for (int j = 0; j < 16; j++) s += s_g[t][j];
                Hf[node] = s + v3[0];
            }
        }
    }
}

template<int K, int NCOL, int TN, int MODE>
__global__ __launch_bounds__(256)
void tiled_gemm_kernel(const float* __restrict__ X, const float* __restrict__ W,
                       const float* __restrict__ v1, const float* __restrict__ v2,
                       const float* __restrict__ v3,
                       uint32* __restrict__ H16, float* __restrict__ Hf,
                       float* __restrict__ AS, float* __restrict__ AD, int n_nodes) {
    gemm_body<K, NCOL, TN, MODE>(blockIdx.x, X, W, v1, v2, v3, H16, Hf, AS, AD, n_nodes);
}

// layer-1 GEMM with CSR fill fused into trailing blocks (independent work;
// fill depends on hist+scan which run before this launch)
template<int K, int NCOL, int TN>
__global__ __launch_bounds__(256)
void gemm_fill_kernel(const float* __restrict__ X, const float* __restrict__ W,
                      const float* __restrict__ v1, const float* __restrict__ v2,
                      uint32* __restrict__ H16, float* __restrict__ AS, float* __restrict__ AD,
                      int n_nodes, int nb_gemm,
                      const int* __restrict__ src, const int* __restrict__ dst,
                      int* __restrict__ pos, int* __restrict__ col, int E, int N) {
    if ((int)blockIdx.x < nb_gemm) {
        gemm_body<K, NCOL, TN, 0>(blockIdx.x, X, W, v1, v2, nullptr, H16, nullptr,
                                  AS, AD, n_nodes);
    } else {
        int tid = (blockIdx.x - nb_gemm) * 256 + threadIdx.x;
        int stride = (gridDim.x - nb_gemm) * 256;
        for (int i = tid; i < E + N; i += stride) {
            if (i < E) {
                int p = atomicAdd(&pos[dst[i]], 1);
                col[p] = src[i];
            } else {
                int nn = i - E;
                int p = atomicAdd(&pos[nn], 1);
                col[p] = nn;
            }
        }
    }
}

// ---------------- degree histogram (standalone; precedes scan) ----------------
__global__ void hist_kernel(const int* __restrict__ dst, int* __restrict__ deg, int E) {
    int e = blockIdx.x * blockDim.x + threadIdx.x;
    if (e < E) atomicAdd(&deg[dst[e]], 1);
}

// ---------------- CSR scan (2 kernels; block-sum scan folded into local pass) ----------------
__global__ void scan_bsum_kernel(const int* __restrict__ deg, int* __restrict__ bsum, int n) {
    __shared__ int s[256];
    int t = threadIdx.x;
    int base = blockIdx.x * 1024;
    int sum = 0;
#pragma unroll
    for (int j = 0; j < 4; j++) {
        int i = base + j * 256 + t;
        if (i < n) sum += deg[i] + 1;   // +1 self-loop
    }
    s[t] = sum;
    __syncthreads();
    for (int off = 128; off; off >>= 1) {
        if (t < off) s[t] += s[t + off];
        __syncthreads();
    }
    if (t == 0) bsum[blockIdx.x] = s[0];
}

__global__ void scan_local_kernel(const int* __restrict__ deg, const int* __restrict__ bsum,
                                  int nb, int* __restrict__ rowptr, int* __restrict__ pos,
                                  int n) {
    __shared__ int s[256];
    __shared__ int boff[257];
    int t = threadIdx.x;
    if (t < nb) boff[t] = bsum[t];
    __syncthreads();
    if (t == 0) {
        int run = 0;
        for (int i = 0; i < nb; i++) { int v = boff[i]; boff[i] = run; run += v; }
        boff[nb] = run;
    }
    __syncthreads();
    if (blockIdx.x == 0 && t == 0) rowptr[n] = boff[nb];

    int base = blockIdx.x * 1024;
    int d[4];
    int sum = 0;
#pragma unroll
    for (int j = 0; j < 4; j++) {
        int i = base + t * 4 + j;
        d[j] = (i < n) ? deg[i] + 1 : 0;
        sum += d[j];
    }
    s[t] = sum;
    __syncthreads();
    for (int off = 1; off < 256; off <<= 1) {
        int x = (t >= off) ? s[t - off] : 0;
        __syncthreads();
        s[t] += x;
        __syncthreads();
    }
    int run = boff[blockIdx.x] + s[t] - sum;
#pragma unroll
    for (int j = 0; j < 4; j++) {
        int i = base + t * 4 + j;
        if (i < n) { rowptr[i] = run; pos[i] = run; }
        run += d[j];
    }
}

// ---------------- GAT aggregation: wave per node, bf16 H rows, no max pass ----------------
__global__ __launch_bounds__(256)
void gat_gather_kernel(const uint32* __restrict__ H16, const float* __restrict__ AS,
                       const float* __restrict__ AD, const int* __restrict__ rowptr,
                       const int* __restrict__ col, const float* __restrict__ bias,
                       float* __restrict__ OUT, int n_nodes) {
    int wid = threadIdx.x >> 6, lane = threadIdx.x & 63;
    int n = blockIdx.x * 4 + wid;
    if (n >= n_nodes) return;   // wave-uniform exit
    int beg = rowptr[n], end = rowptr[n + 1];

    int h = lane & 3, slot = lane >> 2;
    float ad_n = AD[(size_t)n * 4 + h];

    int c = lane;                       // bf16-pair (uint) index within row of 48
    bool cown = c < 48;
    int head_c = cown ? (c / 12) : 0;   // head of channels (2c,2c+1)
    const uint32* __restrict__ Hc = H16 + c;

    float denom = 0.f;
    float2 acc0 = make_float2(0.f, 0.f), acc1 = make_float2(0.f, 0.f);
    float2 acc2 = make_float2(0.f, 0.f), acc3 = make_float2(0.f, 0.f);
    float2 acc4 = make_float2(0.f, 0.f), acc5 = make_float2(0.f, 0.f);
    float2 acc6 = make_float2(0.f, 0.f), acc7 = make_float2(0.f, 0.f);

    for (int base = beg; base < end; base += 16) {
        int ce = base + slot;
        int s_e = 0;
        float ex = 0.f;
        if (ce < end) {
            s_e = col[ce];
            float v = AS[(size_t)s_e * 4 + h] + ad_n;
            v = v > 0.f ? v : 0.2f * v;
            ex = __expf(v);             // bounded scores -> shift-free softmax safe
        }
        denom += ex;
        int cnt = end - base;           // wave-uniform

        int sbv[16];
        float wv[16];
#pragma unroll
        for (int i = 0; i < 16; i++) {
            sbv[i] = __shfl(s_e, i * 4, 64);
            wv[i]  = __shfl(ex,  i * 4 + head_c, 64);
        }

#pragma unroll
        for (int g = 0; g < 16; g += 8) {
            if (g < cnt && cown) {
                uint32 u0 = Hc[(size_t)sbv[g + 0] * 48];
                uint32 u1 = Hc[(size_t)sbv[g + 1] * 48];
                uint32 u2 = Hc[(size_t)sbv[g + 2] * 48];
                uint32 u3 = Hc[(size_t)sbv[g + 3] * 48];
                uint32 u4 = Hc[(size_t)sbv[g + 4] * 48];
                uint32 u5 = Hc[(size_t)sbv[g + 5] * 48];
                uint32 u6 = Hc[(size_t)sbv[g + 6] * 48];
                uint32 u7 = Hc[(size_t)sbv[g + 7] * 48];
                acc0.x = fmaf(__uint_as_float(u0 << 16), wv[g + 0], acc0.x);
                acc0.y = fmaf(__uint_as_float(u0 & 0xffff0000u), wv[g + 0], acc0.y);
                acc1.x = fmaf(__uint_as_float(u1 << 16), wv[g + 1], acc1.x);
                acc1.y = fmaf(__uint_as_float(u1 & 0xffff0000u), wv[g + 1], acc1.y);
                acc2.x = fmaf(__uint_as_float(u2 << 16), wv[g + 2], acc2.x);
                acc2.y = fmaf(__uint_as_float(u2 & 0xffff0000u), wv[g + 2], acc2.y);
                acc3.x = fmaf(__uint_as_float(u3 << 16), wv[g + 3], acc3.x);
                acc3.y = fmaf(__uint_as_float(u3 & 0xffff0000u), wv[g + 3], acc3.y);
                acc4.x = fmaf(__uint_as_float(u4 << 16), wv[g + 4], acc4.x);
                acc4.y = fmaf(__uint_as_float(u4 & 0xffff0000u), wv[g + 4], acc4.y);
                acc5.x = fmaf(__uint_as_float(u5 << 16), wv[g + 5], acc5.x);
                acc5.y = fmaf(__uint_as_float(u5 & 0xffff0000u), wv[g + 5], acc5.y);
                acc6.x = fmaf(__uint_as_float(u6 << 16), wv[g + 6], acc6.x);
                acc6.y = fmaf(__uint_as_float(u6 & 0xffff0000u), wv[g + 6], acc6.y);
                acc7.x = fmaf(__uint_as_float(u7 << 16), wv[g + 7], acc7.x);
                acc7.y = fmaf(__uint_as_float(u7 & 0xffff0000u), wv[g + 7], acc7.y);
            }
        }
    }

#pragma unroll
    for (int m = 4; m <= 32; m <<= 1)
        denom += __shfl_xor(denom, m, 64);
    float den = __shfl(denom, head_c, 64);

    if (cown) {
        float2 a;
        a.x = ((acc0.x + acc1.x) + (acc2.x + acc3.x)) + ((acc4.x + acc5.x) + (acc6.x + acc7.x));
        a.y = ((acc0.y + acc1.y) + (acc2.y + acc3.y)) + ((acc4.y + acc5.y) + (acc6.y + acc7.y));
        float2 b2 = reinterpret_cast<const float2*>(bias)[c];
        float inv = 1.f / (den + 1e-16f);
        float ox = a.x * inv + b2.x;
        float oy = a.y * inv + b2.y;
        ox = ox > 0.f ? ox : (__expf(ox) - 1.f);   // ELU
        oy = oy > 0.f ? oy : (__expf(oy) - 1.f);
        reinterpret_cast<float2*>(OUT)[(size_t)n * 48 + c] = make_float2(ox, oy);
    }
}

// ---------------- pooling: unnormalized weighted segment-sum + denom ----------------
__global__ __launch_bounds__(384)
void pool_accum_kernel(const float* __restrict__ H2, const float* __restrict__ gate,
                       const int* __restrict__ batch, int n_nodes,
                       float* __restrict__ pooled, float* __restrict__ denp) {
    const int NPB = 256;
    int t = threadIdx.x;
    int group = t / 96;
    int c = t - group * 96;
    if (group >= 4) return;
    int nbeg = blockIdx.x * NPB;
    int nend = min(nbeg + NPB, n_nodes);

    float acc = 0.f, dacc = 0.f;
    int curg = -1;
    for (int i = nbeg + group; i < nend; i += 4) {
        int g = batch[i];
        if (g != curg) {
            if (curg >= 0) {
                atomicAdd(&pooled[(size_t)curg * 96 + c], acc);
                if (c == 0) atomicAdd(&denp[curg], dacc);
            }
            acc = 0.f; dacc = 0.f;
            curg = g;
        }
        float ge = __expf(gate[i]);
        acc = fmaf(ge, H2[(size_t)i * 96 + c], acc);
        if (c == 0) dacc += ge;
    }
    if (curg >= 0) {
        atomicAdd(&pooled[(size_t)curg * 96 + c], acc);
        if (c == 0) atomicAdd(&denp[curg], dacc);
    }
}

// ---------------- final MLP (one block per graph); normalizes pooled ----------------
__global__ void final_kernel(const float* __restrict__ pooled, const float* __restrict__ denp,
                             const float* __restrict__ f_w1, const float* __restrict__ f_b1,
                             const float* __restrict__ f_w2, const float* __restrict__ f_b2,
                             float* __restrict__ out) {
    int g = blockIdx.x, t = threadIdx.x;   // 96 threads
    __shared__ float sp[96], sh[96];
    sp[t] = pooled[(size_t)g * 96 + t] / (denp[g] + 1e-16f);
    __syncthreads();
    float a = f_b1[t];
    for (int k = 0; k < 96; k++) a = fmaf(sp[k], f_w1[k * 96 + t], a);
    sh[t] = fmaxf(a, 0.f);
    __syncthreads();
    if (t < 3) {
        float o = f_b2[t];
        for (int k = 0; k < 96; k++) o = fmaf(sh[k], f_w2[k * 3 + t], o);
        out[g * 3 + t] = o;
    }
}

// ---------------- launch ----------------
extern "C" void kernel_launch(void* const* d_in, const int* in_sizes, int n_in,
                              void* d_out, int out_size, void* d_ws, size_t ws_size,
                              hipStream_t stream) {
    const float* x    = (const float*)d_in[0];
    const int*   ei   = (const int*)d_in[1];
    const int*   batch= (const int*)d_in[2];
    const float* W1   = (const float*)d_in[4];
    const float* as1  = (const float*)d_in[5];
    const float* ad1  = (const float*)d_in[6];
    const float* b1   = (const float*)d_in[7];
    const float* W2   = (const float*)d_in[8];
    const float* as2  = (const float*)d_in[9];
    const float* ad2  = (const float*)d_in[10];
    const float* b2   = (const float*)d_in[11];
    const float* g_w1 = (const float*)d_in[12];
    const float* g_b1 = (const float*)d_in[13];
    const float* g_w2 = (const float*)d_in[14];
    const float* g_b2 = (const float*)d_in[15];
    const float* f_w1 = (const float*)d_in[16];
    const float* f_b1 = (const float*)d_in[17];
    const float* f_w2 = (const float*)d_in[18];
    const float* f_b2 = (const float*)d_in[19];
    float* out = (float*)d_out;

    int N = in_sizes[0] / 128;
    int E = in_sizes[1] / 2;
    int G = out_size / 3;
    const int* srcv = ei;
    const int* dstv = ei + E;

    // zero-init region first (deg | pooled | denp) -> single memset
    char* base = (char*)d_ws;
    int*   deg    = (int*)base;
    float* pooled = (float*)(base + (size_t)N * 4);
    float* denp   = (float*)(base + (size_t)N * 4 + (size_t)G * 96 * 4);
    size_t zbytes = (size_t)(N + G * 96 + G) * 4;

    char* p = base + ((zbytes + 255) & ~(size_t)255);
    auto alloc = [&](size_t bytes) {
        char* q = p;
        p += (bytes + 255) & ~(size_t)255;
        return q;
    };
    uint32* hA   = (uint32*)alloc((size_t)N * 48 * 4);   // bf16 x2 per uint
    float* hB    = (float*)alloc((size_t)N * 96 * 4);
    float* AS    = (float*)alloc((size_t)N * 4 * 4);
    float* AD    = (float*)alloc((size_t)N * 4 * 4);
    float* gatev = (float*)alloc((size_t)N * 4);
    int*   pos   = (int*)alloc((size_t)N * 4);
    int*   rowptr= (int*)alloc(((size_t)N + 1) * 4);
    int*   bsum  = (int*)alloc((size_t)256 * 4);
    int*   col   = (int*)alloc((size_t)(E + N) * 4);

    const int B = 256;
    int gemm_blocks = (N + 63) / 64;
    int nb_scan = (N + 1023) / 1024;

    hipMemsetAsync(base, 0, zbytes, stream);

    // CSR prefix: histogram + scan (must precede the fused fill)
    hist_kernel<<<(E + B - 1) / B, B, 0, stream>>>(dstv, deg, E);
    scan_bsum_kernel<<<nb_scan, 256, 0, stream>>>(deg, bsum, N);
    scan_local_kernel<<<nb_scan, 256, 0, stream>>>(deg, bsum, nb_scan, rowptr, pos, N);

    // layer-1 GEMM with CSR fill fused as trailing blocks (independent work overlapped)
    gemm_fill_kernel<128, 96, 6><<<gemm_blocks + 1024, 256, 0, stream>>>(
        x, W1, as1, ad1, hA, AS, AD, N, gemm_blocks, srcv, dstv, pos, col, E, N);

    // layer 1 aggregation
    gat_gather_kernel<<<(N + 3) / 4, 256, 0, stream>>>(hA, AS, AD, rowptr, col, b1, hB, N);
    // layer 2
    tiled_gemm_kernel<96, 96, 6, 0><<<gemm_blocks, 256, 0, stream>>>(
        hB, W2, as2, ad2, nullptr, hA, nullptr, AS, AD, N);
    gat_gather_kernel<<<(N + 3) / 4, 256, 0, stream>>>(hA, AS, AD, rowptr, col, b2, hB, N);

    // pooling
    tiled_gemm_kernel<96, 48, 3, 1><<<gemm_blocks, 256, 0, stream>>>(
        hB, g_w1, g_b1, g_w2, g_b2, nullptr, gatev, nullptr, nullptr, N);
    pool_accum_kernel<<<(N + 255) / 256, 384, 0, stream>>>(
        hB, gatev, batch, N, pooled, denp);
    final_kernel<<<G, 96, 0, stream>>>(pooled, denp, f_w1, f_b1, f_w2, f_b2, out);
}